// Round 2
// baseline (85.621 us; speedup 1.0000x reference)
//
#include <hip/hip_runtime.h>

// DecisionTreePolicy: complete binary tree, depth 15 (32767 nodes).
// Internal nodes: 0..16382 (children always 2i+1 / 2i+2); leaves 16383..32766.
// Traversal = exactly 14 steps from the root; out[b] = leaf_logits[leaf(b)].
//
// R1 lesson: one-thread-per-row made ALL 256 MiB of obs simultaneously
// resident -> L3 couldn't hold lines across the 14 dependent gathers ->
// ~470 MB HBM fetch (14 x 128 B/row). Fix: 65536 threads x 4 sequential
// rows each (contiguous 64 MiB window per pass) so re-reads hit L2/L3.

#define N_NODES   32767
#define N_INTERN  16383
#define N_FEAT    256
#define N_ACT     64
#define BATCH     262144
#define BLOCK     256
#define GRID      256
#define PASSES    (BATCH / (GRID * BLOCK))   // 4
#define DEPTH     14

__global__ __launch_bounds__(BLOCK) void tree_policy_kernel(
    const float* __restrict__ obs,          // [BATCH][N_FEAT]
    const int*   __restrict__ features,     // [N_NODES]
    const float* __restrict__ thresholds,   // [N_NODES]
    const float* __restrict__ leaf_logits,  // [N_NODES][N_ACT]
    float*       __restrict__ out)          // [BATCH][N_ACT]
{
    // Packed tree node: .x = threshold (f32), .y = feature index (int bits).
    // 16384 * 8 B = 128 KiB LDS; 1 block/CU (LDS-bound), 4 waves/CU.
    __shared__ float2 nodes[N_INTERN + 1];

    const int tid = threadIdx.x;

    for (int i = tid; i < N_INTERN; i += BLOCK) {
        nodes[i] = make_float2(thresholds[i], __int_as_float(features[i]));
    }
    __syncthreads();

    const int lane = tid & 63;
    const int r_lo = lane >> 4;    // 0..3: which of 4 rows this lane serves
    const int c4   = lane & 15;    // which float4 chunk of a 64-float row

#pragma unroll
    for (int p = 0; p < PASSES; ++p) {
        // Pass p covers rows [p*65536, (p+1)*65536): a contiguous 64 MiB
        // window of obs, small enough that L3 keeps lines alive across
        // the 14 dependent gathers of each row.
        const long b = (long)p * (GRID * BLOCK) + (long)blockIdx.x * BLOCK + tid;
        const float* row = obs + b * N_FEAT;

        int node = 0;
#pragma unroll
        for (int d = 0; d < DEPTH; ++d) {
            const float2 nd = nodes[node];       // ds_read_b64
            const int f = __float_as_int(nd.y);
            const float x = row[f];              // per-lane gather (L3-warm after 1st touch)
            node = 2 * node + ((x <= nd.x) ? 1 : 2);   // matches reference NaN semantics
        }
        // node = absolute leaf id in [16383, 32766].

        // Wave-cooperative coalesced output: each wave owns 64 consecutive
        // rows; per iteration 4 rows are written as float4 (1 KiB store).
        const long wbase = (long)p * (GRID * BLOCK) + (long)blockIdx.x * BLOCK + (tid & ~63);
#pragma unroll
        for (int it = 0; it < 16; ++it) {
            const int r = it * 4 + r_lo;
            const int leaf_r = __shfl(node, r, 64);
            const float4 v = *(const float4*)(leaf_logits + (size_t)leaf_r * N_ACT + c4 * 4);
            *(float4*)(out + (wbase + r) * N_ACT + c4 * 4) = v;
        }
    }
}

extern "C" void kernel_launch(void* const* d_in, const int* in_sizes, int n_in,
                              void* d_out, int out_size, void* d_ws, size_t ws_size,
                              hipStream_t stream) {
    const float* obs         = (const float*)d_in[0];
    const int*   features    = (const int*)  d_in[1];
    const float* thresholds  = (const float*)d_in[2];
    // d_in[3]/d_in[4] (children) unused: tree is complete by construction.
    const float* leaf_logits = (const float*)d_in[5];
    float*       out         = (float*)d_out;

    tree_policy_kernel<<<dim3(GRID), dim3(BLOCK), 0, stream>>>(
        obs, features, thresholds, leaf_logits, out);
}

// Round 4
// 68.518 us; speedup vs baseline: 1.2496x; 1.2496x over previous
//
#include <hip/hip_runtime.h>

// DecisionTreePolicy — complete binary tree, depth 15 (32767 nodes).
// Internal 0..16382 (children 2i+1/2i+2), leaves 16383..32766 -> exactly 14
// steps from root; out[b] = leaf_logits[leaf(b)].
//
// R1/R2 lesson: scattered per-lane gathers of obs re-fetch every 128B line at
// every depth step (~470 MB HBM, 84us) and NO cache tier held them. R3/R4:
// stream obs through LDS once (coalesced, 256 MB compulsory), keep the WHOLE
// tree in LDS compressed (f32 thr 64KB + u8 feat 16KB), do all 14 gathers as
// ds_read. Prefetch next tile into registers during traversal (T14 split).
// R4 fix: nontemporal builtins need native vector types, not HIP_vector_type.

#define N_INTERN  16383
#define N_FEAT    256
#define N_ACT     64
#define BATCH     262144
#define BLOCK     256
#define GRID      256
#define ROWS_PB   (BATCH / GRID)          // 1024 rows per block
#define TILE_ROWS 64
#define TILES     (ROWS_PB / TILE_ROWS)   // 16
#define DEPTH     14
#define PF_N      16                      // float4 loads/thread/tile: 64KB / 256 thr / 16B

typedef float f32x4 __attribute__((ext_vector_type(4)));   // native vec: ok for nontemporal

struct __align__(16) Smem {
    f32x4         obs4[TILE_ROWS * N_FEAT / 4];  // 65536 B — one obs tile
    float         thr [N_INTERN];                // 65532 B — all internal thresholds
    unsigned char feat[N_INTERN];                // 16383 B — feature ids fit in u8
};  // ~147.4 KB of 160 KB

__global__ __launch_bounds__(BLOCK, 1) void tree_policy_kernel(
    const float* __restrict__ obs,          // [BATCH][N_FEAT]
    const int*   __restrict__ features,     // [N_NODES]
    const float* __restrict__ thresholds,   // [N_NODES]
    const float* __restrict__ leaf_logits,  // [N_NODES][N_ACT]
    float*       __restrict__ out)          // [BATCH][N_ACT]
{
    __shared__ Smem sm;
    const int tid  = threadIdx.x;
    const int lane = tid & 63;

    // ---- pack tree into LDS (one-time, coalesced reads of 64+64 KB, L2) ----
    for (int i = tid; i < N_INTERN; i += BLOCK) {
        sm.thr[i]  = thresholds[i];
        sm.feat[i] = (unsigned char)features[i];
    }

    const long rowBase = (long)blockIdx.x * ROWS_PB;

    // ---- prefetch tile 0 into registers (streaming: nontemporal) ----
    f32x4 pf[PF_N];
    {
        const f32x4* src = (const f32x4*)(obs + rowBase * N_FEAT);
#pragma unroll
        for (int k = 0; k < PF_N; ++k)
            pf[k] = __builtin_nontemporal_load(&src[tid + k * BLOCK]);
    }

    for (int t = 0; t < TILES; ++t) {
        __builtin_amdgcn_sched_barrier(0);
        __builtin_amdgcn_s_barrier();            // A: all waves done reading obs[t-1]
        // regs -> LDS (compiler inserts the vmcnt wait for pf here)
#pragma unroll
        for (int k = 0; k < PF_N; ++k)
            sm.obs4[tid + k * BLOCK] = pf[k];
        // issue prefetch of tile t+1 — stays in flight across the barrier;
        // traversal below is LDS-only so no vmcnt wait touches these loads.
        if (t + 1 < TILES) {
            const f32x4* src =
                (const f32x4*)(obs + (rowBase + (long)(t + 1) * TILE_ROWS) * N_FEAT);
#pragma unroll
            for (int k = 0; k < PF_N; ++k)
                pf[k] = __builtin_nontemporal_load(&src[tid + k * BLOCK]);
        }
        asm volatile("s_waitcnt lgkmcnt(0)" ::: "memory");  // my ds_writes done
        __builtin_amdgcn_s_barrier();            // B: obs[t] (and tree, t=0) visible
        __builtin_amdgcn_sched_barrier(0);       // don't hoist ds_reads above B

        // ---- traversal: row = lane (waves 0-3 redundantly compute the tile) ----
        const float* myrow = (const float*)sm.obs4 + lane * N_FEAT;
        int node = 0;
#pragma unroll
        for (int d = 0; d < DEPTH; ++d) {
            const float th = sm.thr[node];       // ds_read_b32, ~random bank
            const int   f  = sm.feat[node];      // ds_read_u8
            const float x  = myrow[f];           // ds_read_b32 within own row
            node = 2 * node + ((x <= th) ? 1 : 2);   // reference NaN semantics
        }
        // node = leaf id in [16383, 32766]

        // ---- epilogue: fully coalesced float4 stores, leaf rows from L2 ----
        const long outRow0 = rowBase + (long)t * TILE_ROWS;
#pragma unroll
        for (int j = 0; j < 4; ++j) {
            const int g     = j * BLOCK + tid;   // float4 id in tile output [0,1024)
            const int r     = g >> 4;            // row in tile [0,64)
            const int chunk = g & 15;            // float4 chunk within 64-float row
            const int leaf  = __shfl(node, r, 64);
            const f32x4 v   = *(const f32x4*)(leaf_logits + (size_t)leaf * N_ACT + chunk * 4);
            __builtin_nontemporal_store(v, (f32x4*)(out + (outRow0 + r) * N_ACT + chunk * 4));
        }
    }
}

extern "C" void kernel_launch(void* const* d_in, const int* in_sizes, int n_in,
                              void* d_out, int out_size, void* d_ws, size_t ws_size,
                              hipStream_t stream) {
    const float* obs         = (const float*)d_in[0];
    const int*   features    = (const int*)  d_in[1];
    const float* thresholds  = (const float*)d_in[2];
    // d_in[3]/d_in[4] (children) unused: tree is complete by construction.
    const float* leaf_logits = (const float*)d_in[5];
    float*       out         = (float*)d_out;

    tree_policy_kernel<<<dim3(GRID), dim3(BLOCK), 0, stream>>>(
        obs, features, thresholds, leaf_logits, out);
}